// Round 1
// baseline (415.273 us; speedup 1.0000x reference)
//
#include <hip/hip_runtime.h>
#include <math.h>

#define K_DIM 8192
#define M_DIM 8192
#define N_DIM 8
#define RED_BLOCKS 2048    // blocks in the |W| reduction

// ---------------------------------------------------------------------------
// Kernel 1: partial sums of |W|. Grid-stride float4, per-block double partial.
// ---------------------------------------------------------------------------
__global__ __launch_bounds__(256) void k_abssum(const float4* __restrict__ W4,
                                                double* __restrict__ partials,
                                                int n4) {
    int tid = blockIdx.x * blockDim.x + threadIdx.x;
    int stride = gridDim.x * blockDim.x;
    float s0 = 0.f, s1 = 0.f, s2 = 0.f, s3 = 0.f;
    for (int i = tid; i < n4; i += stride) {
        float4 v = W4[i];
        s0 += fabsf(v.x); s1 += fabsf(v.y);
        s2 += fabsf(v.z); s3 += fabsf(v.w);
    }
    float s = (s0 + s1) + (s2 + s3);
    #pragma unroll
    for (int off = 32; off > 0; off >>= 1) s += __shfl_xor(s, off, 64);
    __shared__ float sm[4];
    if ((threadIdx.x & 63) == 0) sm[threadIdx.x >> 6] = s;
    __syncthreads();
    if (threadIdx.x == 0) {
        double t = ((double)sm[0] + (double)sm[1]) +
                   ((double)sm[2] + (double)sm[3]);
        partials[blockIdx.x] = t;
    }
}

// ---------------------------------------------------------------------------
// Kernel 2: final reduce -> s_w, w_deq (replicating reference fp32 ops).
// ---------------------------------------------------------------------------
__global__ __launch_bounds__(256) void k_final(const double* __restrict__ partials,
                                               int nparts,
                                               float* __restrict__ scal) {
    double s = 0.0;
    for (int i = threadIdx.x; i < nparts; i += 256) s += partials[i];
    #pragma unroll
    for (int off = 32; off > 0; off >>= 1) s += __shfl_xor(s, off, 64);
    __shared__ double sm[4];
    if ((threadIdx.x & 63) == 0) sm[threadIdx.x >> 6] = s;
    __syncthreads();
    if (threadIdx.x == 0) {
        double tot = (sm[0] + sm[1]) + (sm[2] + sm[3]);
        float meanf = (float)(tot / (double)((long long)M_DIM * K_DIM));
        float clipped = fmaxf(meanf, 1e-5f);
        float s_w = 1.0f / clipped;    // reference: s_w = 1/clip(mean,1e-5)
        float w_deq = 1.0f / s_w;      // reference: w_deq = 1/s_w (fp32 chain)
        scal[0] = s_w;
        scal[1] = w_deq;
    }
}

// ---------------------------------------------------------------------------
// Kernel 3: activation per-group (64) quantization. One wave == one group.
// x_hat = rint(x / a_scale) * a_scale,  a_scale = max(fmax|xg|/127, 1e-8)
// ---------------------------------------------------------------------------
__global__ __launch_bounds__(256) void k_actq(const float* __restrict__ x,
                                              float* __restrict__ xh) {
    int idx = blockIdx.x * blockDim.x + threadIdx.x;   // 0 .. N*K-1
    float v = x[idx];
    float a = fabsf(v);
    #pragma unroll
    for (int off = 32; off > 0; off >>= 1) a = fmaxf(a, __shfl_xor(a, off, 64));
    float scale = fmaxf(a / 127.0f, 1e-8f);
    float q = rintf(v / scale);
    xh[idx] = q * scale;
}

// ---------------------------------------------------------------------------
// Kernel 4: streaming ternary GEMM, LDS-free.
//   - 2 W rows per wave, 4 waves/block -> 8 rows/block -> 1024 blocks
//     (= 4 blocks/CU, 16 waves/CU: 2x the old occupancy, no barriers,
//      no vmcnt(0) drains in the K loop).
//   - x_hat (256 KB) is read straight from global; it is L2-resident
//     (per-XCD L2 = 4 MiB), total x_hat L2 traffic ~1 GB ~= 30 us at
//     34.5 TB/s, hidden under the 268 MB HBM W-stream.
//   - Accumulation order per (row,n): k = lane*4 + 256*t, t ascending,
//     then the same shuffle tree -> bit-identical to the previous kernel.
// ---------------------------------------------------------------------------
__device__ __forceinline__ float quant1(float w, float s_w) {
    // reference: clip(round(w*s_w), -1, 1); rintf = half-even like np.round
    return fminf(1.0f, fmaxf(-1.0f, rintf(w * s_w)));
}

__global__ __launch_bounds__(256) void k_gemm(const float* __restrict__ W,
                                              const float* __restrict__ xh,
                                              const float* __restrict__ scal,
                                              float* __restrict__ out) {
    const float s_w   = scal[0];
    const float w_deq = scal[1];
    const int wave = threadIdx.x >> 6;
    const int lane = threadIdx.x & 63;
    const int m0 = blockIdx.x * 8 + wave * 2;   // 2 rows per wave

    const float* Wr0 = W + (size_t)(m0 + 0) * K_DIM;
    const float* Wr1 = W + (size_t)(m0 + 1) * K_DIM;

    float acc[2][8];
    #pragma unroll
    for (int r = 0; r < 2; ++r)
        #pragma unroll
        for (int n = 0; n < 8; ++n) acc[r][n] = 0.0f;

    #pragma unroll 2
    for (int it = 0; it < K_DIM / 256; ++it) {
        const int k = it * 256 + lane * 4;
        float4 w0 = *(const float4*)(Wr0 + k);
        float4 w1 = *(const float4*)(Wr1 + k);
        float4 xv[8];
        #pragma unroll
        for (int n = 0; n < 8; ++n)
            xv[n] = *(const float4*)(xh + n * K_DIM + k);

        float4 q0, q1;
        q0.x = quant1(w0.x, s_w); q0.y = quant1(w0.y, s_w);
        q0.z = quant1(w0.z, s_w); q0.w = quant1(w0.w, s_w);
        q1.x = quant1(w1.x, s_w); q1.y = quant1(w1.y, s_w);
        q1.z = quant1(w1.z, s_w); q1.w = quant1(w1.w, s_w);

        #pragma unroll
        for (int n = 0; n < 8; ++n) {
            acc[0][n] = fmaf(q0.x, xv[n].x, acc[0][n]);
            acc[0][n] = fmaf(q0.y, xv[n].y, acc[0][n]);
            acc[0][n] = fmaf(q0.z, xv[n].z, acc[0][n]);
            acc[0][n] = fmaf(q0.w, xv[n].w, acc[0][n]);
            acc[1][n] = fmaf(q1.x, xv[n].x, acc[1][n]);
            acc[1][n] = fmaf(q1.y, xv[n].y, acc[1][n]);
            acc[1][n] = fmaf(q1.z, xv[n].z, acc[1][n]);
            acc[1][n] = fmaf(q1.w, xv[n].w, acc[1][n]);
        }
    }

    // cross-lane reduction + store (same tree/order as before)
    #pragma unroll
    for (int r = 0; r < 2; ++r) {
        #pragma unroll
        for (int n = 0; n < 8; ++n) {
            float v = acc[r][n];
            #pragma unroll
            for (int off = 32; off > 0; off >>= 1) v += __shfl_xor(v, off, 64);
            acc[r][n] = v;
        }
    }
    if (lane == 0) {
        #pragma unroll
        for (int r = 0; r < 2; ++r)
            #pragma unroll
            for (int n = 0; n < 8; ++n)
                out[n * M_DIM + (m0 + r)] = w_deq * acc[r][n];
    }
}

// ---------------------------------------------------------------------------
extern "C" void kernel_launch(void* const* d_in, const int* in_sizes, int n_in,
                              void* d_out, int out_size, void* d_ws, size_t ws_size,
                              hipStream_t stream) {
    const float* x = (const float*)d_in[0];       // [8, 8192] fp32
    const float* W = (const float*)d_in[1];       // [8192, 8192] fp32
    float* out = (float*)d_out;                   // [8, 8192] fp32

    // ws layout: [0,16K) double partials[2048]; [16K,+8) scalars; [32K,+256K) x_hat
    double* partials = (double*)d_ws;
    float* scal = (float*)((char*)d_ws + 16384);
    float* xh = (float*)((char*)d_ws + 32768);

    const int n4 = (M_DIM * K_DIM) / 4;   // 16,777,216 float4

    k_abssum<<<RED_BLOCKS, 256, 0, stream>>>((const float4*)W, partials, n4);
    k_actq<<<(N_DIM * K_DIM) / 256, 256, 0, stream>>>(x, xh);
    k_final<<<1, 256, 0, stream>>>(partials, RED_BLOCKS, scal);
    k_gemm<<<M_DIM / 8, 256, 0, stream>>>(W, xh, scal, out);
}

// Round 2
// 410.773 us; speedup vs baseline: 1.0110x; 1.0110x over previous
//
#include <hip/hip_runtime.h>
#include <math.h>

#define K_DIM 8192
#define M_DIM 8192
#define N_DIM 8
#define RED_BLOCKS 2048        // abssum-role blocks (fp order depends on this)
#define ACTQ_BLOCKS 256        // (N_DIM*K_DIM)/256

// ---------------------------------------------------------------------------
// Kernel 1 (fused): blocks [0,2048) -> partial sums of |W| (grid-stride
// float4, per-block double partial, STRIDE HARDCODED to 2048*256 so the fp
// accumulation order is bit-identical to the previous 2048-block kernel).
// Blocks [2048, 2304) -> activation per-group(64) quantization.
// ---------------------------------------------------------------------------
__global__ __launch_bounds__(256) void k_pre(const float4* __restrict__ W4,
                                             double* __restrict__ partials,
                                             const float* __restrict__ x,
                                             float* __restrict__ xh,
                                             int n4) {
    if (blockIdx.x < RED_BLOCKS) {
        // ---- |W| partial-sum role (fp order identical to old k_abssum) ----
        int tid = blockIdx.x * 256 + threadIdx.x;
        const int stride = RED_BLOCKS * 256;          // NOT gridDim-dependent
        float s0 = 0.f, s1 = 0.f, s2 = 0.f, s3 = 0.f;
        for (int i = tid; i < n4; i += stride) {
            float4 v = W4[i];
            s0 += fabsf(v.x); s1 += fabsf(v.y);
            s2 += fabsf(v.z); s3 += fabsf(v.w);
        }
        float s = (s0 + s1) + (s2 + s3);
        #pragma unroll
        for (int off = 32; off > 0; off >>= 1) s += __shfl_xor(s, off, 64);
        __shared__ float sm[4];
        if ((threadIdx.x & 63) == 0) sm[threadIdx.x >> 6] = s;
        __syncthreads();
        if (threadIdx.x == 0) {
            double t = ((double)sm[0] + (double)sm[1]) +
                       ((double)sm[2] + (double)sm[3]);
            partials[blockIdx.x] = t;
        }
    } else {
        // ---- activation quantization role (identical math to old k_actq) ----
        int idx = (blockIdx.x - RED_BLOCKS) * 256 + threadIdx.x; // 0..N*K-1
        float v = x[idx];
        float a = fabsf(v);
        #pragma unroll
        for (int off = 32; off > 0; off >>= 1) a = fmaxf(a, __shfl_xor(a, off, 64));
        float scale = fmaxf(a / 127.0f, 1e-8f);
        float q = rintf(v / scale);
        xh[idx] = q * scale;
    }
}

// ---------------------------------------------------------------------------
// Kernel 2: streaming ternary GEMM with the final mean-reduce folded into a
// parallel-redundant prologue (bit-identical to the old single-block k_final:
// same per-thread load order, same shuffle tree, same (0+1)+(2+3) combine,
// same fp32 s_w / w_deq chain). LDS-free K loop, 2 rows/wave, 4 waves/block,
// 1024 blocks = 4 blocks/CU; W float4 loads software-pipelined one iteration
// ahead (schedule-only change: accumulation order untouched).
// ---------------------------------------------------------------------------
__device__ __forceinline__ float quant1(float w, float s_w) {
    // reference: clip(round(w*s_w), -1, 1); rintf = half-even like np.round
    return fminf(1.0f, fmaxf(-1.0f, rintf(w * s_w)));
}

__device__ __forceinline__ void fma_step(float acc[2][8],
                                         const float4& w0, const float4& w1,
                                         const float4 xv[8], float s_w) {
    float4 q0, q1;
    q0.x = quant1(w0.x, s_w); q0.y = quant1(w0.y, s_w);
    q0.z = quant1(w0.z, s_w); q0.w = quant1(w0.w, s_w);
    q1.x = quant1(w1.x, s_w); q1.y = quant1(w1.y, s_w);
    q1.z = quant1(w1.z, s_w); q1.w = quant1(w1.w, s_w);
    #pragma unroll
    for (int n = 0; n < 8; ++n) {
        acc[0][n] = fmaf(q0.x, xv[n].x, acc[0][n]);
        acc[0][n] = fmaf(q0.y, xv[n].y, acc[0][n]);
        acc[0][n] = fmaf(q0.z, xv[n].z, acc[0][n]);
        acc[0][n] = fmaf(q0.w, xv[n].w, acc[0][n]);
        acc[1][n] = fmaf(q1.x, xv[n].x, acc[1][n]);
        acc[1][n] = fmaf(q1.y, xv[n].y, acc[1][n]);
        acc[1][n] = fmaf(q1.z, xv[n].z, acc[1][n]);
        acc[1][n] = fmaf(q1.w, xv[n].w, acc[1][n]);
    }
}

__global__ __launch_bounds__(256, 4) void k_gemm(const float* __restrict__ W,
                                                 const float* __restrict__ xh,
                                                 const double* __restrict__ partials,
                                                 float* __restrict__ out) {
    // ---- prologue: replicate old k_final bit-exactly, per block ----
    __shared__ double smd[4];
    __shared__ float s_scal[2];
    {
        double s = 0.0;
        for (int i = threadIdx.x; i < RED_BLOCKS; i += 256) s += partials[i];
        #pragma unroll
        for (int off = 32; off > 0; off >>= 1) s += __shfl_xor(s, off, 64);
        if ((threadIdx.x & 63) == 0) smd[threadIdx.x >> 6] = s;
        __syncthreads();
        if (threadIdx.x == 0) {
            double tot = (smd[0] + smd[1]) + (smd[2] + smd[3]);
            float meanf = (float)(tot / (double)((long long)M_DIM * K_DIM));
            float clipped = fmaxf(meanf, 1e-5f);
            float s_w = 1.0f / clipped;    // reference fp32 chain
            float w_deq = 1.0f / s_w;
            s_scal[0] = s_w;
            s_scal[1] = w_deq;
        }
        __syncthreads();
    }
    const float s_w   = s_scal[0];
    const float w_deq = s_scal[1];

    const int wave = threadIdx.x >> 6;
    const int lane = threadIdx.x & 63;
    const int m0 = blockIdx.x * 8 + wave * 2;   // 2 rows per wave

    const float* Wr0 = W + (size_t)(m0 + 0) * K_DIM;
    const float* Wr1 = W + (size_t)(m0 + 1) * K_DIM;

    float acc[2][8];
    #pragma unroll
    for (int r = 0; r < 2; ++r)
        #pragma unroll
        for (int n = 0; n < 8; ++n) acc[r][n] = 0.0f;

    // software pipeline: preload iteration 0's W vectors
    float4 w0c = *(const float4*)(Wr0 + lane * 4);
    float4 w1c = *(const float4*)(Wr1 + lane * 4);

    #pragma unroll 2
    for (int it = 0; it < K_DIM / 256 - 1; ++it) {
        const int k  = it * 256 + lane * 4;
        const int kn = k + 256;
        float4 w0 = w0c, w1 = w1c;
        w0c = *(const float4*)(Wr0 + kn);        // prefetch next iteration
        w1c = *(const float4*)(Wr1 + kn);
        float4 xv[8];
        #pragma unroll
        for (int n = 0; n < 8; ++n)
            xv[n] = *(const float4*)(xh + n * K_DIM + k);
        fma_step(acc, w0, w1, xv, s_w);
    }
    {   // peeled last iteration
        const int k = (K_DIM / 256 - 1) * 256 + lane * 4;
        float4 xv[8];
        #pragma unroll
        for (int n = 0; n < 8; ++n)
            xv[n] = *(const float4*)(xh + n * K_DIM + k);
        fma_step(acc, w0c, w1c, xv, s_w);
    }

    // cross-lane reduction + store (same tree/order as before)
    #pragma unroll
    for (int r = 0; r < 2; ++r) {
        #pragma unroll
        for (int n = 0; n < 8; ++n) {
            float v = acc[r][n];
            #pragma unroll
            for (int off = 32; off > 0; off >>= 1) v += __shfl_xor(v, off, 64);
            acc[r][n] = v;
        }
    }
    if (lane == 0) {
        #pragma unroll
        for (int r = 0; r < 2; ++r)
            #pragma unroll
            for (int n = 0; n < 8; ++n)
                out[n * M_DIM + (m0 + r)] = w_deq * acc[r][n];
    }
}

// ---------------------------------------------------------------------------
extern "C" void kernel_launch(void* const* d_in, const int* in_sizes, int n_in,
                              void* d_out, int out_size, void* d_ws, size_t ws_size,
                              hipStream_t stream) {
    const float* x = (const float*)d_in[0];       // [8, 8192] fp32
    const float* W = (const float*)d_in[1];       // [8192, 8192] fp32
    float* out = (float*)d_out;                   // [8, 8192] fp32

    // ws layout: [0,16K) double partials[2048]; [32K,+256K) x_hat
    double* partials = (double*)d_ws;
    float* xh = (float*)((char*)d_ws + 32768);

    const int n4 = (M_DIM * K_DIM) / 4;   // 16,777,216 float4

    k_pre<<<RED_BLOCKS + ACTQ_BLOCKS, 256, 0, stream>>>((const float4*)W,
                                                        partials, x, xh, n4);
    k_gemm<<<M_DIM / 8, 256, 0, stream>>>(W, xh, partials, out);
}